// Round 3
// baseline (299.685 us; speedup 1.0000x reference)
//
#include <hip/hip_runtime.h>
#include <math.h>

// Problem constants (fixed by setup_inputs): B=4096 sessions, T=2048 trials.
#define B_SESS 4096
#define T_TR   2048
#define BLK    512          // threads per block (8 waves), one session per block
#define CLT    4            // trials per thread: 512*4 = 2048

// Recurrence per (session, side):  v' = (1-coef)*v + rhs   (affine in v)
//   coef = sum_i alpha_i*w_i,  rhs = sum_i alpha_i*w_i*k_i
//   diff = s1 - s0*v,  delta = rhs - coef*v,  new_v = v + delta
// where m = [same*o, same*no, other*o, other*no]; left: same=cl, right: same=cr.
//
// Strategy: each thread owns 4 consecutive trials, loaded as 3 aligned float4
// straight from global (48 B/lane, lane-stride 48 B, full coverage -> no LDS
// staging). Per-thread affine map composed, in-wave Hillis-Steele shuffle scan
// (6 steps), one barrier to combine 8 wave totals, then replay with stores
// emitted as float4 per trial-pair (lane-stride 32 B, full coverage -> no
// transpose). No register buffers, ~45 VGPR, 128 B LDS -> 32 waves/CU.

__global__ __launch_bounds__(BLK, 8) void qvalue_kernel(
    const float* __restrict__ inp,
    const float* __restrict__ p_asr, const float* __restrict__ p_asu,
    const float* __restrict__ p_adr, const float* __restrict__ p_adu,
    const float* __restrict__ p_ksr, const float* __restrict__ p_ksu,
    const float* __restrict__ p_kdr, const float* __restrict__ p_kdu,
    float* __restrict__ out)
{
    __shared__ float sWT[8 * 4];      // per-wave total maps {AL,BL,AR,BR}

    const int s    = blockIdx.x;
    const int tid  = threadIdx.x;
    const int lane = tid & 63;
    const int w    = tid >> 6;        // wave id 0..7 (wave-uniform)

    // ---- load this thread's 4 trials: 3 aligned float4 ----
    const float4* in4 = (const float4*)(inp + (size_t)s * (T_TR * 3)) + tid * 3;
    float4 x0 = in4[0], x1 = in4[1], x2 = in4[2];
    float cl[CLT] = {x0.x, x0.w, x1.z, x2.y};
    float cr[CLT] = {x0.y, x1.x, x1.w, x2.z};
    float oo[CLT] = {x0.z, x1.y, x2.x, x2.w};

    // ---- parameters (uniform -> scalar regs) ----
    float a0 = 1.f / (1.f + expf(-p_asr[0]));
    float a1 = 1.f / (1.f + expf(-p_asu[0]));
    float a2 = 1.f / (1.f + expf(-p_adr[0]));
    float a3 = 1.f / (1.f + expf(-p_adu[0]));
    float k0 = p_ksr[0], k1 = p_ksu[0], k2 = p_kdr[0], k3 = p_kdu[0];
    float b0 = a0 * k0, b1 = a1 * k1, b2 = a2 * k2, b3 = a3 * k3;

    // ---- Phase A: compose 4-trial affine map per side ----
    float AL = 1.f, BL = 0.f, AR = 1.f, BR = 0.f;
    #pragma unroll
    for (int i = 0; i < CLT; ++i) {
        float o = oo[i], no = 1.f - o;
        float m0 = cl[i] * o, m1 = cl[i] * no, m2 = cr[i] * o, m3 = cr[i] * no;
        float coefL = a0 * m0 + a1 * m1 + a2 * m2 + a3 * m3;
        float rhsL  = b0 * m0 + b1 * m1 + b2 * m2 + b3 * m3;
        float coefR = a0 * m2 + a1 * m3 + a2 * m0 + a3 * m1;
        float rhsR  = b0 * m2 + b1 * m3 + b2 * m0 + b3 * m1;
        float gL = 1.f - coefL, gR = 1.f - coefR;
        AL = gL * AL;  BL = gL * BL + rhsL;
        AR = gR * AR;  BR = gR * BR + rhsR;
    }

    // ---- in-wave inclusive shuffle scan of affine maps (6 steps) ----
    #pragma unroll
    for (int d = 1; d < 64; d <<= 1) {
        float tAL = __shfl_up(AL, d, 64);
        float tBL = __shfl_up(BL, d, 64);
        float tAR = __shfl_up(AR, d, 64);
        float tBR = __shfl_up(BR, d, 64);
        if (lane >= d) {
            BL = AL * tBL + BL;  AL = AL * tAL;
            BR = AR * tBR + BR;  AR = AR * tAR;
        }
    }
    if (lane == 63) {
        sWT[w * 4 + 0] = AL;  sWT[w * 4 + 1] = BL;
        sWT[w * 4 + 2] = AR;  sWT[w * 4 + 3] = BR;
    }
    // exclusive in-wave map (shift one lane; identity at lane 0)
    float eAL = __shfl_up(AL, 1, 64), eBL = __shfl_up(BL, 1, 64);
    float eAR = __shfl_up(AR, 1, 64), eBR = __shfl_up(BR, 1, 64);
    if (lane == 0) { eAL = 1.f; eBL = 0.f; eAR = 1.f; eBR = 0.f; }

    __syncthreads();                  // the only barrier

    // ---- cross-wave exclusive prefix (v0 = 0); <=7 wave-uniform iters ----
    float vbL = 0.f, vbR = 0.f;
    for (int ww = 0; ww < w; ++ww) {
        vbL = sWT[ww * 4 + 0] * vbL + sWT[ww * 4 + 1];
        vbR = sWT[ww * 4 + 2] * vbR + sWT[ww * 4 + 3];
    }
    float vL = eAL * vbL + eBL;
    float vR = eAR * vbR + eBR;

    // ---- replay 4 trials, store one float4 per trial-pair per array ----
    const size_t N2 = (size_t)B_SESS * T_TR * 2;       // floats per output
    float4* ov = (float4*)(out)          + (size_t)s * 1024 + tid * 2;
    float4* of = (float4*)(out + N2)     + (size_t)s * 1024 + tid * 2;
    float4* od = (float4*)(out + 2 * N2) + (size_t)s * 1024 + tid * 2;

    #pragma unroll
    for (int p = 0; p < 2; ++p) {
        float v4[4], f4[4], d4[4];
        #pragma unroll
        for (int j = 0; j < 2; ++j) {
            int i = 2 * p + j;
            float o = oo[i], no = 1.f - o;
            float m0 = cl[i] * o, m1 = cl[i] * no, m2 = cr[i] * o, m3 = cr[i] * no;
            float coefL = a0 * m0 + a1 * m1 + a2 * m2 + a3 * m3;
            float rhsL  = b0 * m0 + b1 * m1 + b2 * m2 + b3 * m3;
            float coefR = a0 * m2 + a1 * m3 + a2 * m0 + a3 * m1;
            float rhsR  = b0 * m2 + b1 * m3 + b2 * m0 + b3 * m1;
            float s0  = m0 + m1 + m2 + m3;
            float s1L = k0 * m0 + k1 * m1 + k2 * m2 + k3 * m3;
            float s1R = k0 * m2 + k1 * m3 + k2 * m0 + k3 * m1;
            float dL = rhsL - coefL * vL;
            float dR = rhsR - coefR * vR;
            f4[2 * j]     = s1L - s0 * vL;
            f4[2 * j + 1] = s1R - s0 * vR;
            vL += dL;  vR += dR;
            v4[2 * j] = vL;  v4[2 * j + 1] = vR;
            d4[2 * j] = dL;  d4[2 * j + 1] = dR;
        }
        ov[p] = make_float4(v4[0], v4[1], v4[2], v4[3]);
        of[p] = make_float4(f4[0], f4[1], f4[2], f4[3]);
        od[p] = make_float4(d4[0], d4[1], d4[2], d4[3]);
    }
}

extern "C" void kernel_launch(void* const* d_in, const int* in_sizes, int n_in,
                              void* d_out, int out_size, void* d_ws, size_t ws_size,
                              hipStream_t stream) {
    (void)in_sizes; (void)n_in; (void)out_size; (void)d_ws; (void)ws_size;
    qvalue_kernel<<<B_SESS, BLK, 0, stream>>>(
        (const float*)d_in[0],
        (const float*)d_in[1], (const float*)d_in[2],
        (const float*)d_in[3], (const float*)d_in[4],
        (const float*)d_in[5], (const float*)d_in[6],
        (const float*)d_in[7], (const float*)d_in[8],
        (float*)d_out);
}